// Round 12
// baseline (276.120 us; speedup 1.0000x reference)
//
#include <hip/hip_runtime.h>
#include <hip/hip_bf16.h>

#define BDIM 384
#define DDIM 1024
#define LDIM 16
#define WD 300
#define CK 320
#define NROWS (BDIM * LDIM)    // 6144
#define FELEM (BDIM * DDIM)    // 393216
#define SELEM (BDIM * BDIM)    // 147456

typedef __attribute__((ext_vector_type(8))) short short8v;     // 8 bf16
typedef _Float16 half8 __attribute__((ext_vector_type(8)));    // 8 fp16
typedef __attribute__((ext_vector_type(4))) float f32x4;

__device__ inline ushort f2bf(float x) {
    union { float f; unsigned u; } c; c.f = x;
    unsigned u = c.u;
    unsigned r = (u + 0x7fffu + ((u >> 16) & 1u)) >> 16;   // RNE
    return (ushort)r;
}

struct CoopArgs {
    const float *embed, *nW, *W1, *W2, *W3, *m, *rr, *tt;
    const int *ntid, *nlen, *ant, *t2i;
    const float *nb, *b1, *b2, *b3;
    ushort *Abf, *BbfT;
    int* rowtok;
    _Float16 *WT1, *WT2, *WT3, *mh, *hh;
    float *S2, *Tr;
    _Float16 *uh, *vh, *rh, *th, *t2h;
    float *inv_r, *inv_t;
    float *Cc;    // concepts output (d_out)
    float *out;   // score output (d_out)
};

// phase unit counts
#define P0_A 1920
#define P0_B (P0_A + 320)
#define P0_T (P0_B + 3072)
#define P0_M (P0_T + 384)
#define P0_N (P0_M + 384)   // 6080: + rt role
#define P1_N 2304           // em1 384 | Tr 384 | concepts64 1536
#define P2_N 384
#define P3_N 384
#define P4_N 144

#define SMEM_BYTES (46080 + 256)

// ---------------- block reductions (256 threads = 4 waves) ----------------
__device__ __forceinline__ float bred_sum(float x, float* sbuf) {
#pragma unroll
    for (int off = 32; off; off >>= 1) x += __shfl_down(x, off);
    __syncthreads();
    if ((threadIdx.x & 63) == 0) sbuf[threadIdx.x >> 6] = x;
    __syncthreads();
    return sbuf[0] + sbuf[1] + sbuf[2] + sbuf[3];
}
__device__ __forceinline__ float bred_max(float x, float* sbuf) {
#pragma unroll
    for (int off = 32; off; off >>= 1) x = fmaxf(x, __shfl_down(x, off));
    __syncthreads();
    if ((threadIdx.x & 63) == 0) sbuf[threadIdx.x >> 6] = x;
    __syncthreads();
    return fmaxf(fmaxf(sbuf[0], sbuf[1]), fmaxf(sbuf[2], sbuf[3]));
}

// ---------------- P0 roles (r11-proven + rt) ----------------
__device__ __forceinline__ void prep_role(const CoopArgs& a, char* smem, int u) {
    float (*tile)[33] = (float(*)[33])smem;
    const int t = threadIdx.x;
    if (u < P0_A) {   // gather embed -> bf16 Abf + rowtok
        int idx = u * 256 + t;
        int row = idx / (CK / 4);
        int q = idx - row * (CK / 4);
        int tok = a.ntid[row];
        int w = a.t2i[tok];
        int eff = (w > 0) ? a.ant[w] : tok;   // `if weight_idx:` falsy-0 semantics
        bool valid = (row & 15) < a.nlen[row >> 4];
        if (q == 0) a.rowtok[row] = valid ? eff : -1;
        ushort4 o = {0, 0, 0, 0};
        if (valid && q < WD / 4) {
            float4 v = *(const float4*)&a.embed[(size_t)eff * WD + q * 4];
            o.x = f2bf(v.x); o.y = f2bf(v.y); o.z = f2bf(v.z); o.w = f2bf(v.w);
        }
        *(ushort4*)&a.Abf[(size_t)row * CK + q * 4] = o;
        return;
    }
    if (u < P0_B) {   // transpose noun_W -> bf16 BbfT
        int bb = u - P0_A;
        const int k0 = (bb % 10) * 32, c0 = (bb / 10) * 32;
        const int r = t >> 3, q = t & 7;
        int k = k0 + r;
        float4 v = {0, 0, 0, 0};
        if (k < WD) v = *(const float4*)&a.nW[(size_t)k * DDIM + c0 + q * 4];
        tile[r][q * 4 + 0] = v.x; tile[r][q * 4 + 1] = v.y;
        tile[r][q * 4 + 2] = v.z; tile[r][q * 4 + 3] = v.w;
        __syncthreads();
        ushort4 o;
        o.x = f2bf(tile[q * 4 + 0][r]);
        o.y = f2bf(tile[q * 4 + 1][r]);
        o.z = f2bf(tile[q * 4 + 2][r]);
        o.w = f2bf(tile[q * 4 + 3][r]);
        *(ushort4*)&a.BbfT[(size_t)(c0 + r) * CK + k0 + q * 4] = o;
        __syncthreads();   // grid-stride reuse guard
        return;
    }
    if (u < P0_T) {   // transW -> fp16 WT[n][k]
        int bb = u - P0_B;
        int z = bb >> 10, rem = bb & 1023;
        const float* W = (z == 0) ? a.W1 : (z == 1) ? a.W2 : a.W3;
        _Float16* WT = (z == 0) ? a.WT1 : (z == 1) ? a.WT2 : a.WT3;
        const int k0 = (rem & 31) * 32, c0 = (rem >> 5) * 32;
        const int r = t >> 3, q = t & 7;
        float4 v = *(const float4*)&W[(size_t)(k0 + r) * DDIM + c0 + q * 4];
        tile[r][q * 4 + 0] = v.x; tile[r][q * 4 + 1] = v.y;
        tile[r][q * 4 + 2] = v.z; tile[r][q * 4 + 3] = v.w;
        __syncthreads();
        union { _Float16 h[4]; ushort4 uu; } o;
        o.h[0] = (_Float16)tile[q * 4 + 0][r];
        o.h[1] = (_Float16)tile[q * 4 + 1][r];
        o.h[2] = (_Float16)tile[q * 4 + 2][r];
        o.h[3] = (_Float16)tile[q * 4 + 3][r];
        *(ushort4*)&WT[(size_t)(c0 + r) * DDIM + k0 + q * 4] = o.uu;
        __syncthreads();
        return;
    }
    if (u < P0_M) {   // m -> fp16
        int bb = u - P0_T;
        int i = bb * 1024 + t * 4;
        float4 v = *(const float4*)&a.m[i];
        union { _Float16 h[4]; ushort4 uu; } o;
        o.h[0] = (_Float16)v.x; o.h[1] = (_Float16)v.y;
        o.h[2] = (_Float16)v.z; o.h[3] = (_Float16)v.w;
        *(ushort4*)&a.mh[i] = o.uu;
        return;
    }
    {                 // rt role: rh/th/t2h/inv_r/inv_t for row b
        int b = u - P0_M;
        float* sbuf = (float*)(smem + 46080);
        const size_t base = (size_t)b * DDIM + t * 4;
        float4 r4 = *(const float4*)&a.rr[base];
        float sr = bred_sum(r4.x * r4.x + r4.y * r4.y + r4.z * r4.z + r4.w * r4.w, sbuf);
        float4 t4 = *(const float4*)&a.tt[base];
        float st = bred_sum(t4.x * t4.x + t4.y * t4.y + t4.z * t4.z + t4.w * t4.w, sbuf);
        union { _Float16 h[4]; ushort4 uu; } o;
        o.h[0] = (_Float16)r4.x; o.h[1] = (_Float16)r4.y;
        o.h[2] = (_Float16)r4.z; o.h[3] = (_Float16)r4.w;
        *(ushort4*)&a.rh[base] = o.uu;
        o.h[0] = (_Float16)t4.x; o.h[1] = (_Float16)t4.y;
        o.h[2] = (_Float16)t4.z; o.h[3] = (_Float16)t4.w;
        *(ushort4*)&a.th[base] = o.uu;
        o.h[0] = (_Float16)(t4.x * t4.x); o.h[1] = (_Float16)(t4.y * t4.y);
        o.h[2] = (_Float16)(t4.z * t4.z); o.h[3] = (_Float16)(t4.w * t4.w);
        *(ushort4*)&a.t2h[base] = o.uu;
        if (t == 0) {
            a.inv_r[b] = 1.f / sqrtf(sr);
            a.inv_t[b] = 1.f / sqrtf(st);
        }
    }
}

// ---------------- em GEMM body (256 thr, 4 waves, 1 acc) — r9/r11 proven ----------------
template <int MODE>
__device__ __forceinline__ void emgemm_body256(const _Float16* __restrict__ Ah,
                                               const _Float16* __restrict__ WT,
                                               const float* __restrict__ bias,
                                               float* __restrict__ outF,
                                               _Float16* __restrict__ outH,
                                               int bm, int bn,
                                               _Float16* As, _Float16* Bs) {
    const int tid = threadIdx.x;
    const int lane = tid & 63;
    const int w = tid >> 6;
    const int hr = (w & 1) * 16, hc = (w >> 1) * 16;
    const int frow = lane & 15, fk = lane >> 4;
    const int srow = tid >> 3, spart = tid & 7;

    f32x4 acc = {0.f, 0.f, 0.f, 0.f};
    int4 pa, pb;
    constexpr int NK = DDIM / 64;  // 16

#define E_LOAD(ks)                                                                  \
    {                                                                               \
        const int k0_ = (ks) * 64 + spart * 8;                                      \
        pa = *(const int4*)&Ah[(size_t)(bm + srow) * DDIM + k0_];                   \
        pb = *(const int4*)&WT[(size_t)(bn + srow) * DDIM + k0_];                   \
    }
#define E_STORE(buf)                                                                \
    {                                                                               \
        *(int4*)&As[(buf) * 2304 + srow * 72 + spart * 8] = pa;                     \
        *(int4*)&Bs[(buf) * 2304 + srow * 72 + spart * 8] = pb;                     \
    }

    E_LOAD(0);
    E_STORE(0);
    __syncthreads();
    int cur = 0;

    for (int ks = 0; ks < NK; ++ks) {
        if (ks + 1 < NK) E_LOAD(ks + 1);
#pragma unroll
        for (int kk = 0; kk < 2; ++kk) {
            half8 av = *(const half8*)&As[cur * 2304 + (hr + frow) * 72 + kk * 32 + fk * 8];
            half8 bv = *(const half8*)&Bs[cur * 2304 + (hc + frow) * 72 + kk * 32 + fk * 8];
            acc = __builtin_amdgcn_mfma_f32_16x16x32_f16(av, bv, acc, 0, 0, 0);
        }
        if (ks + 1 < NK) E_STORE(cur ^ 1);
        __syncthreads();
        cur ^= 1;
    }
#undef E_LOAD
#undef E_STORE

    const int col = bn + hc + frow;
    const float bv = bias[col];
#pragma unroll
    for (int r2 = 0; r2 < 4; ++r2) {
        int row = bm + hr + fk * 4 + r2;
        float v = acc[r2] + bv;
        if (MODE == 1)
            outH[(size_t)row * DDIM + col] = (_Float16)fmaxf(v, 0.f);
        else
            outF[(size_t)row * DDIM + col] = v;
    }
}

// ---------------- concepts64 (r11-proven, + trailing sync for grid-stride reuse) ---------
__device__ __forceinline__ void concepts64(int cu, const CoopArgs& a, char* smem) {
    ushort* CAs = (ushort*)smem;                 // [2][2560]
    ushort* CBs = (ushort*)(smem + 10240);       // [2][2560]
    float*  cst = (float*)smem;                  // [64*68] aliases after K-loop
    int* stok = (int*)(smem + 20480);            // [64]

    const int tid = threadIdx.x;
    const int bm = (cu % 96) * 64, bn = (cu / 96) * 64;
    if (tid < 64) stok[tid] = a.rowtok[bm + tid];

    const int w = tid >> 6, lane = tid & 63;
    const int wr = (w & 1) * 32, wc = (w >> 1) * 32;
    const int frow = lane & 15, fk = lane >> 4;
    const int srow = tid >> 2, spart = tid & 3;

    f32x4 acc[2][2];
#pragma unroll
    for (int i = 0; i < 2; ++i)
#pragma unroll
        for (int j = 0; j < 2; ++j) acc[i][j] = (f32x4){0.f, 0.f, 0.f, 0.f};

    int4 pa, pb;
    constexpr int NK = CK / 32;  // 10

#define C_LOAD(ks)                                                                   \
    {                                                                                \
        const int k0_ = (ks) * 32;                                                   \
        pa = *(const int4*)&a.Abf[(size_t)(bm + srow) * CK + k0_ + spart * 8];       \
        pb = *(const int4*)&a.BbfT[(size_t)(bn + srow) * CK + k0_ + spart * 8];      \
    }
#define C_STORE(buf)                                                                 \
    {                                                                                \
        *(int4*)&CAs[(buf) * 2560 + srow * 40 + spart * 8] = pa;                     \
        *(int4*)&CBs[(buf) * 2560 + srow * 40 + spart * 8] = pb;                     \
    }

    C_LOAD(0);
    C_STORE(0);
    __syncthreads();
    int cur = 0;

    for (int ks = 0; ks < NK; ++ks) {
        if (ks + 1 < NK) C_LOAD(ks + 1);
        short8v av[2], bv[2];
#pragma unroll
        for (int i = 0; i < 2; ++i)
            av[i] = *(const short8v*)&CAs[cur * 2560 + (wr + i * 16 + frow) * 40 + fk * 8];
#pragma unroll
        for (int j = 0; j < 2; ++j)
            bv[j] = *(const short8v*)&CBs[cur * 2560 + (wc + j * 16 + frow) * 40 + fk * 8];
#pragma unroll
        for (int i = 0; i < 2; ++i)
#pragma unroll
            for (int j = 0; j < 2; ++j)
                acc[i][j] = __builtin_amdgcn_mfma_f32_16x16x32_bf16(av[i], bv[j], acc[i][j], 0, 0, 0);
        if (ks + 1 < NK) C_STORE(cur ^ 1);
        __syncthreads();
        cur ^= 1;
    }
#undef C_LOAD
#undef C_STORE

#pragma unroll
    for (int i = 0; i < 2; ++i)
#pragma unroll
        for (int j = 0; j < 2; ++j)
#pragma unroll
            for (int r2 = 0; r2 < 4; ++r2) {
                int row = wr + i * 16 + fk * 4 + r2;
                int col = wc + j * 16 + frow;
                cst[row * 68 + col] = acc[i][j][r2];
            }
    __syncthreads();

#pragma unroll
    for (int it = 0; it < 4; ++it) {
        int f = it * 256 + tid;
        int seg = f & 15;
        int row = f >> 4;
        float4 o = *(const float4*)&cst[row * 68 + seg * 4];
        int colb = seg * 4;
        float4 bv = *(const float4*)&a.nb[bn + colb];
        bool zero = (stok[row] < 0);
        o.x = zero ? 0.f : o.x + bv.x;
        o.y = zero ? 0.f : o.y + bv.y;
        o.z = zero ? 0.f : o.z + bv.z;
        o.w = zero ? 0.f : o.w + bv.w;
        *(float4*)&a.Cc[(size_t)(bm + row) * DDIM + bn + colb] = o;
    }
    __syncthreads();   // grid-stride reuse guard (cst aliases CAs)
}

// ---------------- row_uv: per-row max + ||Tr||, sum-cancelled softmax ----------------
// uh = 32*Tr_hat*E, vh = (32E)^2, E = exp(s - rowmax)  ->  EM = (uh.t)/sqrt(vh.t2)
__device__ __forceinline__ void row_uv(const CoopArgs& a, char* smem, int b) {
    float* sbuf = (float*)(smem + 46080);
    const int tid = threadIdx.x;
    const size_t base = (size_t)b * DDIM + tid * 4;

    const float4 s4 = *(const float4*)&a.S2[base];
    float mx = fmaxf(fmaxf(s4.x, s4.y), fmaxf(s4.z, s4.w));
    mx = bred_max(mx, sbuf);

    const float4 tr4 = *(const float4*)&a.Tr[base];
    float ss = tr4.x * tr4.x + tr4.y * tr4.y + tr4.z * tr4.z + tr4.w * tr4.w;
    ss = bred_sum(ss, sbuf);
    float invn = 32.f / sqrtf(ss);

    float e0 = expf(s4.x - mx), e1 = expf(s4.y - mx), e2 = expf(s4.z - mx), e3 = expf(s4.w - mx);
    union { _Float16 h[4]; ushort4 uu; } o;
    o.h[0] = (_Float16)(tr4.x * invn * e0);
    o.h[1] = (_Float16)(tr4.y * invn * e1);
    o.h[2] = (_Float16)(tr4.z * invn * e2);
    o.h[3] = (_Float16)(tr4.w * invn * e3);
    *(ushort4*)&a.uh[base] = o.uu;
    float q0 = 32.f * e0, q1 = 32.f * e1, q2 = 32.f * e2, q3 = 32.f * e3;
    o.h[0] = (_Float16)(q0 * q0); o.h[1] = (_Float16)(q1 * q1);
    o.h[2] = (_Float16)(q2 * q2); o.h[3] = (_Float16)(q3 * q3);
    *(ushort4*)&a.vh[base] = o.uu;
}

// ---------------- score256: 4-wave 32x32, 3 dots, K-step 64, dbuf ----------------
__device__ __forceinline__ void score256(const CoopArgs& a, char* smem, int u) {
    _Float16* Us = (_Float16*)smem;
    _Float16* Vs = (_Float16*)(smem + 9216);
    _Float16* Rs = (_Float16*)(smem + 18432);
    _Float16* Ts = (_Float16*)(smem + 27648);
    _Float16* Qs = (_Float16*)(smem + 36864);

    const int tid = threadIdx.x;
    const int bm = (u % 12) * 32, bn = (u / 12) * 32;
    const int lane = tid & 63, w = tid >> 6;
    const int r0 = (w & 1) * 16, c0 = (w >> 1) * 16;
    const int frow = lane & 15, fk = lane >> 4;
    const int srow = tid >> 3, spart = tid & 7;

    f32x4 an = {0.f, 0.f, 0.f, 0.f}, ad = an, ai = an;
    int4 pu, pv, pr, pt, pq;
    constexpr int NK = DDIM / 64;  // 16

#define SC_LOAD(ks)                                                                  \
    {                                                                                \
        const size_t mo = (size_t)(bm + srow) * DDIM + (ks) * 64 + spart * 8;        \
        const size_t no = (size_t)(bn + srow) * DDIM + (ks) * 64 + spart * 8;        \
        pu = *(const int4*)&a.uh[mo]; pv = *(const int4*)&a.vh[mo];                  \
        pr = *(const int4*)&a.rh[mo];                                                \
        pt = *(const int4*)&a.th[no]; pq = *(const int4*)&a.t2h[no];                 \
    }
#define SC_STORE(buf)                                                                \
    {                                                                                \
        const int lo = (buf) * 2304 + srow * 72 + spart * 8;                         \
        *(int4*)&Us[lo] = pu; *(int4*)&Vs[lo] = pv; *(int4*)&Rs[lo] = pr;            \
        *(int4*)&Ts[lo] = pt; *(int4*)&Qs[lo] = pq;                                  \
    }

    SC_LOAD(0);
    SC_STORE(0);
    __syncthreads();
    int cur = 0;

    for (int ks = 0; ks < NK; ++ks) {
        if (ks + 1 < NK) SC_LOAD(ks + 1);
#pragma unroll
        for (int kk = 0; kk < 2; ++kk) {
            const int ao = cur * 2304 + (r0 + frow) * 72 + kk * 32 + fk * 8;
            const int bo = cur * 2304 + (c0 + frow) * 72 + kk * 32 + fk * 8;
            half8 au = *(const half8*)&Us[ao];
            half8 av = *(const half8*)&Vs[ao];
            half8 ar = *(const half8*)&Rs[ao];
            half8 bt = *(const half8*)&Ts[bo];
            half8 bq = *(const half8*)&Qs[bo];
            an = __builtin_amdgcn_mfma_f32_16x16x32_f16(au, bt, an, 0, 0, 0);
            ad = __builtin_amdgcn_mfma_f32_16x16x32_f16(av, bq, ad, 0, 0, 0);
            ai = __builtin_amdgcn_mfma_f32_16x16x32_f16(ar, bt, ai, 0, 0, 0);
        }
        if (ks + 1 < NK) SC_STORE(cur ^ 1);
        __syncthreads();
        cur ^= 1;
    }
#undef SC_LOAD
#undef SC_STORE

    const int col = bn + c0 + frow;
    const float it = a.inv_t[col];
#pragma unroll
    for (int r2 = 0; r2 < 4; ++r2) {
        int row = bm + r0 + fk * 4 + r2;
        float ir = a.inv_r[row];
        a.out[(size_t)row * BDIM + col] = an[r2] / sqrtf(ad[r2]) + ai[r2] * ir * it;
    }
}

// ---------------- phase dispatcher ----------------
__device__ __forceinline__ void run_phase(const CoopArgs& a, char* smem, int phase, int u) {
    if (phase == 0) {
        prep_role(a, smem, u);
    } else if (phase == 1) {
        if (u < 384) {
            int bm = (u % 12) * 32, bn = (u / 12) * 32;
            emgemm_body256<1>(a.mh, a.WT1, a.b1, nullptr, a.hh, bm, bn,
                              (_Float16*)smem, (_Float16*)(smem + 9216));
        } else if (u < 768) {
            int v = u - 384;
            int bm = (v % 12) * 32, bn = (v / 12) * 32;
            emgemm_body256<0>(a.mh, a.WT3, a.b3, a.Tr, nullptr, bm, bn,
                              (_Float16*)smem, (_Float16*)(smem + 9216));
        } else {
            concepts64(u - 768, a, smem);
        }
    } else if (phase == 2) {
        int bm = (u % 12) * 32, bn = (u / 12) * 32;
        emgemm_body256<0>(a.hh, a.WT2, a.b2, a.S2, nullptr, bm, bn,
                          (_Float16*)smem, (_Float16*)(smem + 9216));
    } else if (phase == 3) {
        row_uv(a, smem, u);
    } else {
        score256(a, smem, u);
    }
}

// ---------------- grid barrier: coherent-load poll (no RMW, no cached spin) -------------
// r7 failed: relaxed agent load spun on stale per-XCD L2 (~90us = eviction time).
// r8 failed: RMW poll saturated single-line LLC RMW throughput (queueing ~90us).
// Fix: arrival = one atomicAdd; poll = sc0 sc1 (L1+L2-bypass) plain LOAD from LLC.
__device__ __forceinline__ unsigned cload(const unsigned* p) {
    unsigned v;
    asm volatile("global_load_dword %0, %1, off sc0 sc1\n\ts_waitcnt vmcnt(0)"
                 : "=v"(v) : "v"(p) : "memory");
    return v;
}
__device__ __forceinline__ void gbar(unsigned* c, unsigned target) {
    __syncthreads();
    if (threadIdx.x == 0) {
        __threadfence();                 // release
        atomicAdd(c, 1u);
        while (cload(c) < target) __builtin_amdgcn_s_sleep(8);
        __threadfence();                 // acquire
    }
    __syncthreads();
}

__global__ __launch_bounds__(256) void coop_all(CoopArgs a, unsigned* cnt, int G) {
    __shared__ __align__(16) char smem[SMEM_BYTES];
    const int bid = blockIdx.x;
    for (int u = bid; u < P0_N; u += G) run_phase(a, smem, 0, u);
    gbar(cnt + 0, (unsigned)G);
    for (int u = bid; u < P1_N; u += G) run_phase(a, smem, 1, u);
    gbar(cnt + 16, (unsigned)G);
    for (int u = bid; u < P2_N; u += G) run_phase(a, smem, 2, u);
    gbar(cnt + 32, (unsigned)G);
    for (int u = bid; u < P3_N; u += G) run_phase(a, smem, 3, u);
    gbar(cnt + 48, (unsigned)G);
    for (int u = bid; u < P4_N; u += G) run_phase(a, smem, 4, u);
}

// fallback: one launch per phase (no barriers needed)
template <int PHASE>
__global__ __launch_bounds__(256) void phase_k(CoopArgs a) {
    __shared__ __align__(16) char smem[SMEM_BYTES];
    run_phase(a, smem, PHASE, blockIdx.x);
}

extern "C" void kernel_launch(void* const* d_in, const int* in_sizes, int n_in, void* d_out,
                              int out_size, void* d_ws, size_t ws_size, hipStream_t stream) {
    CoopArgs a;
    a.rr = (const float*)d_in[0];
    a.m = (const float*)d_in[1];
    a.tt = (const float*)d_in[2];
    a.ntid = (const int*)d_in[3];
    a.nlen = (const int*)d_in[4];
    a.ant = (const int*)d_in[5];
    a.embed = (const float*)d_in[6];
    a.nW = (const float*)d_in[7];
    a.nb = (const float*)d_in[8];
    a.W1 = (const float*)d_in[9];
    a.b1 = (const float*)d_in[10];
    a.W2 = (const float*)d_in[11];
    a.b2 = (const float*)d_in[12];
    a.W3 = (const float*)d_in[13];
    a.b3 = (const float*)d_in[14];
    a.t2i = (const int*)d_in[15];

    a.out = (float*)d_out;
    a.Cc = a.out + (size_t)SELEM;

    char* base = (char*)d_ws;
    size_t off = 0;
    auto alloc = [&](size_t bytes) { char* p = base + off; off += (bytes + 255) & ~(size_t)255; return p; };
    unsigned* cnt = (unsigned*)alloc(256);
    a.rowtok = (int*)alloc(NROWS * 4);
    a.inv_r = (float*)alloc(BDIM * 4);
    a.inv_t = (float*)alloc(BDIM * 4);
    a.Abf = (ushort*)alloc((size_t)NROWS * CK * 2);
    a.BbfT = (ushort*)alloc((size_t)DDIM * CK * 2);
    a.WT1 = (_Float16*)alloc((size_t)DDIM * DDIM * 2);
    a.WT2 = (_Float16*)alloc((size_t)DDIM * DDIM * 2);
    a.WT3 = (_Float16*)alloc((size_t)DDIM * DDIM * 2);
    a.mh = (_Float16*)alloc((size_t)FELEM * 2);
    a.hh = (_Float16*)alloc((size_t)FELEM * 2);
    a.S2 = (float*)alloc((size_t)FELEM * 4);
    a.Tr = (float*)alloc((size_t)FELEM * 4);
    a.uh = (_Float16*)alloc((size_t)FELEM * 2);
    a.vh = (_Float16*)alloc((size_t)FELEM * 2);
    a.rh = (_Float16*)alloc((size_t)FELEM * 2);
    a.th = (_Float16*)alloc((size_t)FELEM * 2);
    a.t2h = (_Float16*)alloc((size_t)FELEM * 2);

    int dev = 0;
    (void)hipGetDevice(&dev);
    int cus = 0;
    (void)hipDeviceGetAttribute(&cus, hipDeviceAttributeMultiprocessorCount, dev);
    int nb = 0;
    hipError_t qe = hipOccupancyMaxActiveBlocksPerMultiprocessor(
        &nb, reinterpret_cast<const void*>(coop_all), 256, 0);
    long G = (qe == hipSuccess && nb > 0 && cus > 0) ? (long)nb * cus : 0;
    if (G > 768) G = 768;

    if (G >= 64) {
        hipMemsetAsync(cnt, 0, 256, stream);
        coop_all<<<dim3((unsigned)G), 256, 0, stream>>>(a, cnt, (int)G);
    } else {
        phase_k<0><<<P0_N, 256, 0, stream>>>(a);
        phase_k<1><<<P1_N, 256, 0, stream>>>(a);
        phase_k<2><<<P2_N, 256, 0, stream>>>(a);
        phase_k<3><<<P3_N, 256, 0, stream>>>(a);
        phase_k<4><<<P4_N, 256, 0, stream>>>(a);
    }
}

// Round 13
// 58.653 us; speedup vs baseline: 4.7077x; 4.7077x over previous
//
#include <hip/hip_runtime.h>
#include <hip/hip_bf16.h>

#define BDIM 384
#define DDIM 1024
#define LDIM 16
#define WD 300
#define CK 320
#define NROWS (BDIM * LDIM)    // 6144
#define FELEM (BDIM * DDIM)    // 393216
#define SELEM (BDIM * BDIM)    // 147456

typedef __attribute__((ext_vector_type(8))) short short8v;     // 8 bf16
typedef _Float16 half8 __attribute__((ext_vector_type(8)));    // 8 fp16
typedef __attribute__((ext_vector_type(4))) float f32x4;

__device__ inline ushort f2bf(float x) {
    union { float f; unsigned u; } c; c.f = x;
    unsigned u = c.u;
    unsigned r = (u + 0x7fffu + ((u >> 16) & 1u)) >> 16;   // RNE
    return (ushort)r;
}

struct CoopArgs {
    const float *embed, *nW, *W1, *W2, *W3, *m, *rr, *tt;
    const int *ntid, *nlen, *ant, *t2i;
    const float *nb, *b1, *b2, *b3;
    ushort *Abf, *BbfT;
    int* rowtok;
    _Float16 *WT1, *WT2, *WT3, *mh, *hh;
    float *S2, *Tr;
    _Float16 *uh, *vh, *rh, *th, *t2h;
    float *inv_r, *inv_t;
    float *Cc;    // concepts output (d_out)
    float *out;   // score output (d_out)
};

// phase unit counts
#define P0_A 1920
#define P0_B (P0_A + 320)
#define P0_T (P0_B + 3072)
#define P0_M (P0_T + 384)
#define P0_N (P0_M + 384)   // 6080: prepA | prepB | transW | cvt_m | rt
#define P1_N 2304           // em1 384 | Tr 384 | concepts64 1536
#define P2_N 384
#define P3_N 384
#define P4_N 144

// ---------------- block reductions (256 threads = 4 waves) ----------------
__device__ __forceinline__ float bred_sum(float x, float* sbuf) {
#pragma unroll
    for (int off = 32; off; off >>= 1) x += __shfl_down(x, off);
    __syncthreads();
    if ((threadIdx.x & 63) == 0) sbuf[threadIdx.x >> 6] = x;
    __syncthreads();
    return sbuf[0] + sbuf[1] + sbuf[2] + sbuf[3];
}
__device__ __forceinline__ float bred_max(float x, float* sbuf) {
#pragma unroll
    for (int off = 32; off; off >>= 1) x = fmaxf(x, __shfl_down(x, off));
    __syncthreads();
    if ((threadIdx.x & 63) == 0) sbuf[threadIdx.x >> 6] = x;
    __syncthreads();
    return fmaxf(fmaxf(sbuf[0], sbuf[1]), fmaxf(sbuf[2], sbuf[3]));
}

// ---------------- phase 0: prep (r12-verified roles) ----------------
__global__ __launch_bounds__(256) void prep_k(CoopArgs a) {
    __shared__ float tile[32][33];
    __shared__ float sbuf[4];
    const int u = blockIdx.x, t = threadIdx.x;

    if (u < P0_A) {   // gather embed -> bf16 Abf + rowtok
        int idx = u * 256 + t;
        int row = idx / (CK / 4);
        int q = idx - row * (CK / 4);
        int tok = a.ntid[row];
        int w = a.t2i[tok];
        int eff = (w > 0) ? a.ant[w] : tok;   // `if weight_idx:` falsy-0 semantics
        bool valid = (row & 15) < a.nlen[row >> 4];
        if (q == 0) a.rowtok[row] = valid ? eff : -1;
        ushort4 o = {0, 0, 0, 0};
        if (valid && q < WD / 4) {
            float4 v = *(const float4*)&a.embed[(size_t)eff * WD + q * 4];
            o.x = f2bf(v.x); o.y = f2bf(v.y); o.z = f2bf(v.z); o.w = f2bf(v.w);
        }
        *(ushort4*)&a.Abf[(size_t)row * CK + q * 4] = o;
        return;
    }
    if (u < P0_B) {   // transpose noun_W -> bf16 BbfT
        int bb = u - P0_A;
        const int k0 = (bb % 10) * 32, c0 = (bb / 10) * 32;
        const int r = t >> 3, q = t & 7;
        int k = k0 + r;
        float4 v = {0, 0, 0, 0};
        if (k < WD) v = *(const float4*)&a.nW[(size_t)k * DDIM + c0 + q * 4];
        tile[r][q * 4 + 0] = v.x; tile[r][q * 4 + 1] = v.y;
        tile[r][q * 4 + 2] = v.z; tile[r][q * 4 + 3] = v.w;
        __syncthreads();
        ushort4 o;
        o.x = f2bf(tile[q * 4 + 0][r]);
        o.y = f2bf(tile[q * 4 + 1][r]);
        o.z = f2bf(tile[q * 4 + 2][r]);
        o.w = f2bf(tile[q * 4 + 3][r]);
        *(ushort4*)&a.BbfT[(size_t)(c0 + r) * CK + k0 + q * 4] = o;
        return;
    }
    if (u < P0_T) {   // transW -> fp16 WT[n][k]
        int bb = u - P0_B;
        int z = bb >> 10, rem = bb & 1023;
        const float* W = (z == 0) ? a.W1 : (z == 1) ? a.W2 : a.W3;
        _Float16* WT = (z == 0) ? a.WT1 : (z == 1) ? a.WT2 : a.WT3;
        const int k0 = (rem & 31) * 32, c0 = (rem >> 5) * 32;
        const int r = t >> 3, q = t & 7;
        float4 v = *(const float4*)&W[(size_t)(k0 + r) * DDIM + c0 + q * 4];
        tile[r][q * 4 + 0] = v.x; tile[r][q * 4 + 1] = v.y;
        tile[r][q * 4 + 2] = v.z; tile[r][q * 4 + 3] = v.w;
        __syncthreads();
        union { _Float16 h[4]; ushort4 uu; } o;
        o.h[0] = (_Float16)tile[q * 4 + 0][r];
        o.h[1] = (_Float16)tile[q * 4 + 1][r];
        o.h[2] = (_Float16)tile[q * 4 + 2][r];
        o.h[3] = (_Float16)tile[q * 4 + 3][r];
        *(ushort4*)&WT[(size_t)(c0 + r) * DDIM + k0 + q * 4] = o.uu;
        return;
    }
    if (u < P0_M) {   // m -> fp16
        int bb = u - P0_T;
        int i = bb * 1024 + t * 4;
        float4 v = *(const float4*)&a.m[i];
        union { _Float16 h[4]; ushort4 uu; } o;
        o.h[0] = (_Float16)v.x; o.h[1] = (_Float16)v.y;
        o.h[2] = (_Float16)v.z; o.h[3] = (_Float16)v.w;
        *(ushort4*)&a.mh[i] = o.uu;
        return;
    }
    {                 // rt role: rh/th/t2h/inv_r/inv_t for row b
        int b = u - P0_M;
        const size_t base = (size_t)b * DDIM + t * 4;
        float4 r4 = *(const float4*)&a.rr[base];
        float sr = bred_sum(r4.x * r4.x + r4.y * r4.y + r4.z * r4.z + r4.w * r4.w, sbuf);
        float4 t4 = *(const float4*)&a.tt[base];
        float st = bred_sum(t4.x * t4.x + t4.y * t4.y + t4.z * t4.z + t4.w * t4.w, sbuf);
        union { _Float16 h[4]; ushort4 uu; } o;
        o.h[0] = (_Float16)r4.x; o.h[1] = (_Float16)r4.y;
        o.h[2] = (_Float16)r4.z; o.h[3] = (_Float16)r4.w;
        *(ushort4*)&a.rh[base] = o.uu;
        o.h[0] = (_Float16)t4.x; o.h[1] = (_Float16)t4.y;
        o.h[2] = (_Float16)t4.z; o.h[3] = (_Float16)t4.w;
        *(ushort4*)&a.th[base] = o.uu;
        o.h[0] = (_Float16)(t4.x * t4.x); o.h[1] = (_Float16)(t4.y * t4.y);
        o.h[2] = (_Float16)(t4.z * t4.z); o.h[3] = (_Float16)(t4.w * t4.w);
        *(ushort4*)&a.t2h[base] = o.uu;
        if (t == 0) {
            a.inv_r[b] = 1.f / sqrtf(sr);
            a.inv_t[b] = 1.f / sqrtf(st);
        }
    }
}

// ---------------- em GEMM body (256 thr, 4 waves, 1 acc) — r9/r11/r12 proven -------------
template <int MODE>
__device__ __forceinline__ void emgemm_body256(const _Float16* __restrict__ Ah,
                                               const _Float16* __restrict__ WT,
                                               const float* __restrict__ bias,
                                               float* __restrict__ outF,
                                               _Float16* __restrict__ outH,
                                               int bm, int bn,
                                               _Float16* As, _Float16* Bs) {
    const int tid = threadIdx.x;
    const int lane = tid & 63;
    const int w = tid >> 6;
    const int hr = (w & 1) * 16, hc = (w >> 1) * 16;
    const int frow = lane & 15, fk = lane >> 4;
    const int srow = tid >> 3, spart = tid & 7;

    f32x4 acc = {0.f, 0.f, 0.f, 0.f};
    int4 pa, pb;
    constexpr int NK = DDIM / 64;  // 16

#define E_LOAD(ks)                                                                  \
    {                                                                               \
        const int k0_ = (ks) * 64 + spart * 8;                                      \
        pa = *(const int4*)&Ah[(size_t)(bm + srow) * DDIM + k0_];                   \
        pb = *(const int4*)&WT[(size_t)(bn + srow) * DDIM + k0_];                   \
    }
#define E_STORE(buf)                                                                \
    {                                                                               \
        *(int4*)&As[(buf) * 2304 + srow * 72 + spart * 8] = pa;                     \
        *(int4*)&Bs[(buf) * 2304 + srow * 72 + spart * 8] = pb;                     \
    }

    E_LOAD(0);
    E_STORE(0);
    __syncthreads();
    int cur = 0;

    for (int ks = 0; ks < NK; ++ks) {
        if (ks + 1 < NK) E_LOAD(ks + 1);
#pragma unroll
        for (int kk = 0; kk < 2; ++kk) {
            half8 av = *(const half8*)&As[cur * 2304 + (hr + frow) * 72 + kk * 32 + fk * 8];
            half8 bv = *(const half8*)&Bs[cur * 2304 + (hc + frow) * 72 + kk * 32 + fk * 8];
            acc = __builtin_amdgcn_mfma_f32_16x16x32_f16(av, bv, acc, 0, 0, 0);
        }
        if (ks + 1 < NK) E_STORE(cur ^ 1);
        __syncthreads();
        cur ^= 1;
    }
#undef E_LOAD
#undef E_STORE

    const int col = bn + hc + frow;
    const float bv = bias[col];
#pragma unroll
    for (int r2 = 0; r2 < 4; ++r2) {
        int row = bm + hr + fk * 4 + r2;
        float v = acc[r2] + bv;
        if (MODE == 1)
            outH[(size_t)row * DDIM + col] = (_Float16)fmaxf(v, 0.f);
        else
            outF[(size_t)row * DDIM + col] = v;
    }
}

// ---------------- concepts64 (r11/r12 proven) ----------------
__device__ __forceinline__ void concepts64(int cu, const CoopArgs& a, char* smem) {
    ushort* CAs = (ushort*)smem;                 // [2][2560]
    ushort* CBs = (ushort*)(smem + 10240);       // [2][2560]
    float*  cst = (float*)smem;                  // [64*68] aliases after K-loop
    int* stok = (int*)(smem + 20480);            // [64]

    const int tid = threadIdx.x;
    const int bm = (cu % 96) * 64, bn = (cu / 96) * 64;
    if (tid < 64) stok[tid] = a.rowtok[bm + tid];

    const int w = tid >> 6, lane = tid & 63;
    const int wr = (w & 1) * 32, wc = (w >> 1) * 32;
    const int frow = lane & 15, fk = lane >> 4;
    const int srow = tid >> 2, spart = tid & 3;

    f32x4 acc[2][2];
#pragma unroll
    for (int i = 0; i < 2; ++i)
#pragma unroll
        for (int j = 0; j < 2; ++j) acc[i][j] = (f32x4){0.f, 0.f, 0.f, 0.f};

    int4 pa, pb;
    constexpr int NK = CK / 32;  // 10

#define C_LOAD(ks)                                                                   \
    {                                                                                \
        const int k0_ = (ks) * 32;                                                   \
        pa = *(const int4*)&a.Abf[(size_t)(bm + srow) * CK + k0_ + spart * 8];       \
        pb = *(const int4*)&a.BbfT[(size_t)(bn + srow) * CK + k0_ + spart * 8];      \
    }
#define C_STORE(buf)                                                                 \
    {                                                                                \
        *(int4*)&CAs[(buf) * 2560 + srow * 40 + spart * 8] = pa;                     \
        *(int4*)&CBs[(buf) * 2560 + srow * 40 + spart * 8] = pb;                     \
    }

    C_LOAD(0);
    C_STORE(0);
    __syncthreads();
    int cur = 0;

    for (int ks = 0; ks < NK; ++ks) {
        if (ks + 1 < NK) C_LOAD(ks + 1);
        short8v av[2], bv[2];
#pragma unroll
        for (int i = 0; i < 2; ++i)
            av[i] = *(const short8v*)&CAs[cur * 2560 + (wr + i * 16 + frow) * 40 + fk * 8];
#pragma unroll
        for (int j = 0; j < 2; ++j)
            bv[j] = *(const short8v*)&CBs[cur * 2560 + (wc + j * 16 + frow) * 40 + fk * 8];
#pragma unroll
        for (int i = 0; i < 2; ++i)
#pragma unroll
            for (int j = 0; j < 2; ++j)
                acc[i][j] = __builtin_amdgcn_mfma_f32_16x16x32_bf16(av[i], bv[j], acc[i][j], 0, 0, 0);
        if (ks + 1 < NK) C_STORE(cur ^ 1);
        __syncthreads();
        cur ^= 1;
    }
#undef C_LOAD
#undef C_STORE

#pragma unroll
    for (int i = 0; i < 2; ++i)
#pragma unroll
        for (int j = 0; j < 2; ++j)
#pragma unroll
            for (int r2 = 0; r2 < 4; ++r2) {
                int row = wr + i * 16 + fk * 4 + r2;
                int col = wc + j * 16 + frow;
                cst[row * 68 + col] = acc[i][j][r2];
            }
    __syncthreads();

#pragma unroll
    for (int it = 0; it < 4; ++it) {
        int f = it * 256 + tid;
        int seg = f & 15;
        int row = f >> 4;
        float4 o = *(const float4*)&cst[row * 68 + seg * 4];
        int colb = seg * 4;
        float4 bv = *(const float4*)&a.nb[bn + colb];
        bool zero = (stok[row] < 0);
        o.x = zero ? 0.f : o.x + bv.x;
        o.y = zero ? 0.f : o.y + bv.y;
        o.z = zero ? 0.f : o.z + bv.z;
        o.w = zero ? 0.f : o.w + bv.w;
        *(float4*)&a.Cc[(size_t)(bm + row) * DDIM + bn + colb] = o;
    }
}

// ---------------- phase 1: em1 (0..383) | Tr (384..767) | concepts64 (768..2303) ---------
__global__ __launch_bounds__(256) void mega1_k(CoopArgs a) {
    __shared__ __align__(16) char smem[20480 + 256];
    const int u = blockIdx.x;
    if (u < 384) {
        int bm = (u % 12) * 32, bn = (u / 12) * 32;
        emgemm_body256<1>(a.mh, a.WT1, a.b1, nullptr, a.hh, bm, bn,
                          (_Float16*)smem, (_Float16*)(smem + 9216));
    } else if (u < 768) {
        int v = u - 384;
        int bm = (v % 12) * 32, bn = (v / 12) * 32;
        emgemm_body256<0>(a.mh, a.WT3, a.b3, a.Tr, nullptr, bm, bn,
                          (_Float16*)smem, (_Float16*)(smem + 9216));
    } else {
        concepts64(u - 768, a, smem);
    }
}

// ---------------- phase 2: S2 = hh @ WT2 + b2 ----------------
__global__ __launch_bounds__(256) void em2_k(CoopArgs a) {
    __shared__ __align__(16) char smem[18432];
    const int u = blockIdx.x;
    int bm = (u % 12) * 32, bn = (u / 12) * 32;
    emgemm_body256<0>(a.hh, a.WT2, a.b2, a.S2, nullptr, bm, bn,
                      (_Float16*)smem, (_Float16*)(smem + 9216));
}

// ---------------- phase 3: row_uv — sum-cancelled softmax (r12-verified) ----------------
// uh = 32*Tr_hat*E, vh = (32E)^2, E = exp(s - rowmax)  ->  EM = (uh.t)/sqrt(vh.t2)
__global__ __launch_bounds__(256) void row_k(CoopArgs a) {
    __shared__ float sbuf[4];
    const int b = blockIdx.x, tid = threadIdx.x;
    const size_t base = (size_t)b * DDIM + tid * 4;

    const float4 s4 = *(const float4*)&a.S2[base];
    float mx = fmaxf(fmaxf(s4.x, s4.y), fmaxf(s4.z, s4.w));
    mx = bred_max(mx, sbuf);

    const float4 tr4 = *(const float4*)&a.Tr[base];
    float ss = tr4.x * tr4.x + tr4.y * tr4.y + tr4.z * tr4.z + tr4.w * tr4.w;
    ss = bred_sum(ss, sbuf);
    float invn = 32.f / sqrtf(ss);

    float e0 = expf(s4.x - mx), e1 = expf(s4.y - mx), e2 = expf(s4.z - mx), e3 = expf(s4.w - mx);
    union { _Float16 h[4]; ushort4 uu; } o;
    o.h[0] = (_Float16)(tr4.x * invn * e0);
    o.h[1] = (_Float16)(tr4.y * invn * e1);
    o.h[2] = (_Float16)(tr4.z * invn * e2);
    o.h[3] = (_Float16)(tr4.w * invn * e3);
    *(ushort4*)&a.uh[base] = o.uu;
    float q0 = 32.f * e0, q1 = 32.f * e1, q2 = 32.f * e2, q3 = 32.f * e3;
    o.h[0] = (_Float16)(q0 * q0); o.h[1] = (_Float16)(q1 * q1);
    o.h[2] = (_Float16)(q2 * q2); o.h[3] = (_Float16)(q3 * q3);
    *(ushort4*)&a.vh[base] = o.uu;
}

// ---------------- phase 4: score256 (r12-verified) ----------------
__global__ __launch_bounds__(256) void score_k(CoopArgs a) {
    __shared__ __align__(16) char smem[46080];
    _Float16* Us = (_Float16*)smem;
    _Float16* Vs = (_Float16*)(smem + 9216);
    _Float16* Rs = (_Float16*)(smem + 18432);
    _Float16* Ts = (_Float16*)(smem + 27648);
    _Float16* Qs = (_Float16*)(smem + 36864);

    const int u = blockIdx.x;
    const int tid = threadIdx.x;
    const int bm = (u % 12) * 32, bn = (u / 12) * 32;
    const int lane = tid & 63, w = tid >> 6;
    const int r0 = (w & 1) * 16, c0 = (w >> 1) * 16;
    const int frow = lane & 15, fk = lane >> 4;
    const int srow = tid >> 3, spart = tid & 7;

    f32x4 an = {0.f, 0.f, 0.f, 0.f}, ad = an, ai = an;
    int4 pu, pv, pr, pt, pq;
    constexpr int NK = DDIM / 64;  // 16

#define SC_LOAD(ks)                                                                  \
    {                                                                                \
        const size_t mo = (size_t)(bm + srow) * DDIM + (ks) * 64 + spart * 8;        \
        const size_t no = (size_t)(bn + srow) * DDIM + (ks) * 64 + spart * 8;        \
        pu = *(const int4*)&a.uh[mo]; pv = *(const int4*)&a.vh[mo];                  \
        pr = *(const int4*)&a.rh[mo];                                                \
        pt = *(const int4*)&a.th[no]; pq = *(const int4*)&a.t2h[no];                 \
    }
#define SC_STORE(buf)                                                                \
    {                                                                                \
        const int lo = (buf) * 2304 + srow * 72 + spart * 8;                         \
        *(int4*)&Us[lo] = pu; *(int4*)&Vs[lo] = pv; *(int4*)&Rs[lo] = pr;            \
        *(int4*)&Ts[lo] = pt; *(int4*)&Qs[lo] = pq;                                  \
    }

    SC_LOAD(0);
    SC_STORE(0);
    __syncthreads();
    int cur = 0;

    for (int ks = 0; ks < NK; ++ks) {
        if (ks + 1 < NK) SC_LOAD(ks + 1);
#pragma unroll
        for (int kk = 0; kk < 2; ++kk) {
            const int ao = cur * 2304 + (r0 + frow) * 72 + kk * 32 + fk * 8;
            const int bo = cur * 2304 + (c0 + frow) * 72 + kk * 32 + fk * 8;
            half8 au = *(const half8*)&Us[ao];
            half8 av = *(const half8*)&Vs[ao];
            half8 ar = *(const half8*)&Rs[ao];
            half8 bt = *(const half8*)&Ts[bo];
            half8 bq = *(const half8*)&Qs[bo];
            an = __builtin_amdgcn_mfma_f32_16x16x32_f16(au, bt, an, 0, 0, 0);
            ad = __builtin_amdgcn_mfma_f32_16x16x32_f16(av, bq, ad, 0, 0, 0);
            ai = __builtin_amdgcn_mfma_f32_16x16x32_f16(ar, bt, ai, 0, 0, 0);
        }
        if (ks + 1 < NK) SC_STORE(cur ^ 1);
        __syncthreads();
        cur ^= 1;
    }
#undef SC_LOAD
#undef SC_STORE

    const int col = bn + c0 + frow;
    const float it = a.inv_t[col];
#pragma unroll
    for (int r2 = 0; r2 < 4; ++r2) {
        int row = bm + r0 + fk * 4 + r2;
        float ir = a.inv_r[row];
        a.out[(size_t)row * BDIM + col] = an[r2] / sqrtf(ad[r2]) + ai[r2] * ir * it;
    }
}

extern "C" void kernel_launch(void* const* d_in, const int* in_sizes, int n_in, void* d_out,
                              int out_size, void* d_ws, size_t ws_size, hipStream_t stream) {
    CoopArgs a;
    a.rr = (const float*)d_in[0];
    a.m = (const float*)d_in[1];
    a.tt = (const float*)d_in[2];
    a.ntid = (const int*)d_in[3];
    a.nlen = (const int*)d_in[4];
    a.ant = (const int*)d_in[5];
    a.embed = (const float*)d_in[6];
    a.nW = (const float*)d_in[7];
    a.nb = (const float*)d_in[8];
    a.W1 = (const float*)d_in[9];
    a.b1 = (const float*)d_in[10];
    a.W2 = (const float*)d_in[11];
    a.b2 = (const float*)d_in[12];
    a.W3 = (const float*)d_in[13];
    a.b3 = (const float*)d_in[14];
    a.t2i = (const int*)d_in[15];

    a.out = (float*)d_out;
    a.Cc = a.out + (size_t)SELEM;

    char* base = (char*)d_ws;
    size_t off = 0;
    auto alloc = [&](size_t bytes) { char* p = base + off; off += (bytes + 255) & ~(size_t)255; return p; };
    a.rowtok = (int*)alloc(NROWS * 4);
    a.inv_r = (float*)alloc(BDIM * 4);
    a.inv_t = (float*)alloc(BDIM * 4);
    a.Abf = (ushort*)alloc((size_t)NROWS * CK * 2);
    a.BbfT = (ushort*)alloc((size_t)DDIM * CK * 2);
    a.WT1 = (_Float16*)alloc((size_t)DDIM * DDIM * 2);
    a.WT2 = (_Float16*)alloc((size_t)DDIM * DDIM * 2);
    a.WT3 = (_Float16*)alloc((size_t)DDIM * DDIM * 2);
    a.mh = (_Float16*)alloc((size_t)FELEM * 2);
    a.hh = (_Float16*)alloc((size_t)FELEM * 2);
    a.S2 = (float*)alloc((size_t)FELEM * 4);
    a.Tr = (float*)alloc((size_t)FELEM * 4);
    a.uh = (_Float16*)alloc((size_t)FELEM * 2);
    a.vh = (_Float16*)alloc((size_t)FELEM * 2);
    a.rh = (_Float16*)alloc((size_t)FELEM * 2);
    a.th = (_Float16*)alloc((size_t)FELEM * 2);
    a.t2h = (_Float16*)alloc((size_t)FELEM * 2);

    prep_k<<<P0_N, 256, 0, stream>>>(a);
    mega1_k<<<P1_N, 256, 0, stream>>>(a);
    em2_k<<<P2_N, 256, 0, stream>>>(a);
    row_k<<<P3_N, 256, 0, stream>>>(a);
    score_k<<<P4_N, 256, 0, stream>>>(a);
}

// Round 14
// 57.363 us; speedup vs baseline: 4.8136x; 1.0225x over previous
//
#include <hip/hip_runtime.h>
#include <hip/hip_bf16.h>

#define BDIM 384
#define DDIM 1024
#define LDIM 16
#define WD 300
#define CK 320                 // concepts K padded to 32-multiple for MFMA
#define NROWS (BDIM * LDIM)    // 6144
#define FELEM (BDIM * DDIM)    // 393216
#define SELEM (BDIM * BDIM)    // 147456

typedef __attribute__((ext_vector_type(8))) short short8v;     // 8 bf16
typedef _Float16 half8 __attribute__((ext_vector_type(8)));    // 8 fp16
typedef __attribute__((ext_vector_type(4))) float f32x4;

__device__ inline ushort f2bf(float x) {
    union { float f; unsigned u; } c; c.f = x;
    unsigned u = c.u;
    unsigned r = (u + 0x7fffu + ((u >> 16) & 1u)) >> 16;   // RNE
    return (ushort)r;
}

// ---------------- prep_all: fused prepA-gather | prepB | 3x transW | cvt_m ----------------
#define PRE_A 1920
#define PRE_B (PRE_A + 320)
#define PRE_T (PRE_B + 3072)
#define PRE_M (PRE_T + 384)
__global__ __launch_bounds__(256) void prep_all(
    const float* __restrict__ embed, const int* __restrict__ ntid,
    const int* __restrict__ nlen, const int* __restrict__ ant, const int* __restrict__ t2i,
    ushort* __restrict__ Abf, int* __restrict__ rowtok,
    const float* __restrict__ nW, ushort* __restrict__ BbfT,
    const float* __restrict__ W1, const float* __restrict__ W2, const float* __restrict__ W3,
    _Float16* __restrict__ WT1, _Float16* __restrict__ WT2, _Float16* __restrict__ WT3,
    const float* __restrict__ m, _Float16* __restrict__ mh) {
    __shared__ float tile[32][33];
    const int b = blockIdx.x, t = threadIdx.x;

    if (b < PRE_A) {
        int idx = b * 256 + t;
        int row = idx / (CK / 4);
        int q = idx - row * (CK / 4);
        int tok = ntid[row];
        int w = t2i[tok];
        int eff = (w > 0) ? ant[w] : tok;            // `if weight_idx:` falsy-0 semantics
        bool valid = (row & 15) < nlen[row >> 4];
        if (q == 0) rowtok[row] = valid ? eff : -1;
        ushort4 o = {0, 0, 0, 0};
        if (valid && q < WD / 4) {
            float4 v = *(const float4*)&embed[(size_t)eff * WD + q * 4];
            o.x = f2bf(v.x); o.y = f2bf(v.y); o.z = f2bf(v.z); o.w = f2bf(v.w);
        }
        *(ushort4*)&Abf[(size_t)row * CK + q * 4] = o;
        return;
    }
    if (b < PRE_B) {
        int bb = b - PRE_A;
        const int k0 = (bb % 10) * 32, c0 = (bb / 10) * 32;
        const int r = t >> 3, q = t & 7;
        int k = k0 + r;
        float4 v = {0, 0, 0, 0};
        if (k < WD) v = *(const float4*)&nW[(size_t)k * DDIM + c0 + q * 4];
        tile[r][q * 4 + 0] = v.x; tile[r][q * 4 + 1] = v.y;
        tile[r][q * 4 + 2] = v.z; tile[r][q * 4 + 3] = v.w;
        __syncthreads();
        ushort4 o;
        o.x = f2bf(tile[q * 4 + 0][r]);
        o.y = f2bf(tile[q * 4 + 1][r]);
        o.z = f2bf(tile[q * 4 + 2][r]);
        o.w = f2bf(tile[q * 4 + 3][r]);
        *(ushort4*)&BbfT[(size_t)(c0 + r) * CK + k0 + q * 4] = o;
        return;
    }
    if (b < PRE_T) {
        int bb = b - PRE_B;
        int z = bb >> 10, rem = bb & 1023;
        const float* W = (z == 0) ? W1 : (z == 1) ? W2 : W3;
        _Float16* WT = (z == 0) ? WT1 : (z == 1) ? WT2 : WT3;
        const int k0 = (rem & 31) * 32, c0 = (rem >> 5) * 32;
        const int r = t >> 3, q = t & 7;
        float4 v = *(const float4*)&W[(size_t)(k0 + r) * DDIM + c0 + q * 4];
        tile[r][q * 4 + 0] = v.x; tile[r][q * 4 + 1] = v.y;
        tile[r][q * 4 + 2] = v.z; tile[r][q * 4 + 3] = v.w;
        __syncthreads();
        union { _Float16 h[4]; ushort4 u; } o;
        o.h[0] = (_Float16)tile[q * 4 + 0][r];
        o.h[1] = (_Float16)tile[q * 4 + 1][r];
        o.h[2] = (_Float16)tile[q * 4 + 2][r];
        o.h[3] = (_Float16)tile[q * 4 + 3][r];
        *(ushort4*)&WT[(size_t)(c0 + r) * DDIM + k0 + q * 4] = o.u;
        return;
    }
    {
        int bb = b - PRE_T;
        int i = bb * 1024 + t * 4;
        float4 v = *(const float4*)&m[i];
        union { _Float16 h[4]; ushort4 u; } o;
        o.h[0] = (_Float16)v.x; o.h[1] = (_Float16)v.y;
        o.h[2] = (_Float16)v.z; o.h[3] = (_Float16)v.w;
        *(ushort4*)&mh[i] = o.u;
    }
}

// ---------------- em GEMM body (256 thr, 4 waves, 1 acc) — r9/r11 proven ----------------
template <int MODE>
__device__ __forceinline__ void emgemm_body256(const _Float16* __restrict__ Ah,
                                               const _Float16* __restrict__ WT,
                                               const float* __restrict__ bias,
                                               float* __restrict__ outF,
                                               _Float16* __restrict__ outH,
                                               int bm, int bn,
                                               _Float16* As, _Float16* Bs) {  // each [2][2304]
    const int tid = threadIdx.x;
    const int lane = tid & 63;
    const int w = tid >> 6;
    const int hr = (w & 1) * 16, hc = (w >> 1) * 16;
    const int frow = lane & 15, fk = lane >> 4;
    const int srow = tid >> 3, spart = tid & 7;

    f32x4 acc = {0.f, 0.f, 0.f, 0.f};
    int4 pa, pb;
    constexpr int NK = DDIM / 64;  // 16

#define E_LOAD(ks)                                                                  \
    {                                                                               \
        const int k0_ = (ks) * 64 + spart * 8;                                      \
        pa = *(const int4*)&Ah[(size_t)(bm + srow) * DDIM + k0_];                   \
        pb = *(const int4*)&WT[(size_t)(bn + srow) * DDIM + k0_];                   \
    }
#define E_STORE(buf)                                                                \
    {                                                                               \
        *(int4*)&As[(buf) * 2304 + srow * 72 + spart * 8] = pa;                     \
        *(int4*)&Bs[(buf) * 2304 + srow * 72 + spart * 8] = pb;                     \
    }

    E_LOAD(0);
    E_STORE(0);
    __syncthreads();
    int cur = 0;

    for (int ks = 0; ks < NK; ++ks) {
        if (ks + 1 < NK) E_LOAD(ks + 1);
#pragma unroll
        for (int kk = 0; kk < 2; ++kk) {
            half8 a = *(const half8*)&As[cur * 2304 + (hr + frow) * 72 + kk * 32 + fk * 8];
            half8 b = *(const half8*)&Bs[cur * 2304 + (hc + frow) * 72 + kk * 32 + fk * 8];
            acc = __builtin_amdgcn_mfma_f32_16x16x32_f16(a, b, acc, 0, 0, 0);
        }
        if (ks + 1 < NK) E_STORE(cur ^ 1);
        __syncthreads();
        cur ^= 1;
    }
#undef E_LOAD
#undef E_STORE

    const int col = bn + hc + frow;
    const float bv = bias[col];
#pragma unroll
    for (int r2 = 0; r2 < 4; ++r2) {
        int row = bm + hr + fk * 4 + r2;
        float v = acc[r2] + bv;
        if (MODE == 1)
            outH[(size_t)row * DDIM + col] = (_Float16)fmaxf(v, 0.f);
        else
            outF[(size_t)row * DDIM + col] = v;
    }
}

// ---------------- concepts64: 64x64 MFMA bf16 tile, K=CK, dbuf, 20.5KB LDS ----------------
__device__ __forceinline__ void concepts64(int cu, const ushort* __restrict__ Abf,
                                           const ushort* __restrict__ BbfT,
                                           const int* __restrict__ rowtok,
                                           const float* __restrict__ nbias,
                                           float* __restrict__ C, char* smem) {
    ushort* CAs = (ushort*)smem;                 // [2][2560]
    ushort* CBs = (ushort*)(smem + 10240);       // [2][2560]
    float*  cst = (float*)smem;                  // [64*68] = 17408B (aliases after K-loop)
    int* stok = (int*)(smem + 20480);            // [64]

    const int tid = threadIdx.x;
    const int bm = (cu % 96) * 64, bn = (cu / 96) * 64;
    if (tid < 64) stok[tid] = rowtok[bm + tid];

    const int w = tid >> 6, lane = tid & 63;
    const int wr = (w & 1) * 32, wc = (w >> 1) * 32;
    const int frow = lane & 15, fk = lane >> 4;
    const int srow = tid >> 2, spart = tid & 3;

    f32x4 acc[2][2];
#pragma unroll
    for (int i = 0; i < 2; ++i)
#pragma unroll
        for (int j = 0; j < 2; ++j) acc[i][j] = (f32x4){0.f, 0.f, 0.f, 0.f};

    int4 pa, pb;
    constexpr int NK = CK / 32;  // 10

#define C_LOAD(ks)                                                                   \
    {                                                                                \
        const int k0_ = (ks) * 32;                                                   \
        pa = *(const int4*)&Abf[(size_t)(bm + srow) * CK + k0_ + spart * 8];         \
        pb = *(const int4*)&BbfT[(size_t)(bn + srow) * CK + k0_ + spart * 8];        \
    }
#define C_STORE(buf)                                                                 \
    {                                                                                \
        *(int4*)&CAs[(buf) * 2560 + srow * 40 + spart * 8] = pa;                     \
        *(int4*)&CBs[(buf) * 2560 + srow * 40 + spart * 8] = pb;                     \
    }

    C_LOAD(0);
    C_STORE(0);
    __syncthreads();
    int cur = 0;

    for (int ks = 0; ks < NK; ++ks) {
        if (ks + 1 < NK) C_LOAD(ks + 1);
        short8v av[2], bv[2];
#pragma unroll
        for (int i = 0; i < 2; ++i)
            av[i] = *(const short8v*)&CAs[cur * 2560 + (wr + i * 16 + frow) * 40 + fk * 8];
#pragma unroll
        for (int j = 0; j < 2; ++j)
            bv[j] = *(const short8v*)&CBs[cur * 2560 + (wc + j * 16 + frow) * 40 + fk * 8];
#pragma unroll
        for (int i = 0; i < 2; ++i)
#pragma unroll
            for (int j = 0; j < 2; ++j)
                acc[i][j] = __builtin_amdgcn_mfma_f32_16x16x32_bf16(av[i], bv[j], acc[i][j], 0, 0, 0);
        if (ks + 1 < NK) C_STORE(cur ^ 1);
        __syncthreads();
        cur ^= 1;
    }
#undef C_LOAD
#undef C_STORE

#pragma unroll
    for (int i = 0; i < 2; ++i)
#pragma unroll
        for (int j = 0; j < 2; ++j)
#pragma unroll
            for (int r2 = 0; r2 < 4; ++r2) {
                int row = wr + i * 16 + fk * 4 + r2;
                int col = wc + j * 16 + frow;
                cst[row * 68 + col] = acc[i][j][r2];
            }
    __syncthreads();

#pragma unroll
    for (int it = 0; it < 4; ++it) {
        int f = it * 256 + tid;          // 1024 float4 total
        int seg = f & 15;
        int row = f >> 4;
        float4 o = *(const float4*)&cst[row * 68 + seg * 4];
        int colb = seg * 4;
        float4 bv = *(const float4*)&nbias[bn + colb];
        bool zero = (stok[row] < 0);
        o.x = zero ? 0.f : o.x + bv.x;
        o.y = zero ? 0.f : o.y + bv.y;
        o.z = zero ? 0.f : o.z + bv.z;
        o.w = zero ? 0.f : o.w + bv.w;
        *(float4*)&C[(size_t)(bm + row) * DDIM + bn + colb] = o;
    }
}

// ---------------- mega1: em1 (0..383) | Tr (384..767) | concepts64 (768..2303) ----------
__global__ __launch_bounds__(256) void mega1(const _Float16* __restrict__ mh,
                                             const _Float16* __restrict__ WT1,
                                             const _Float16* __restrict__ WT3,
                                             const float* __restrict__ b1,
                                             const float* __restrict__ b3,
                                             _Float16* __restrict__ hh,
                                             float* __restrict__ Tr,
                                             const ushort* __restrict__ Abf,
                                             const ushort* __restrict__ BbfT,
                                             const int* __restrict__ rowtok,
                                             const float* __restrict__ nbias,
                                             float* __restrict__ C) {
    __shared__ __align__(16) char smem[20480 + 256];
    const int blk = blockIdx.x;
    if (blk < 384) {
        int bm = (blk % 12) * 32, bn = (blk / 12) * 32;
        emgemm_body256<1>(mh, WT1, b1, nullptr, hh, bm, bn,
                          (_Float16*)smem, (_Float16*)(smem + 9216));
    } else if (blk < 768) {
        int v = blk - 384;
        int bm = (v % 12) * 32, bn = (v / 12) * 32;
        emgemm_body256<0>(mh, WT3, b3, Tr, nullptr, bm, bn,
                          (_Float16*)smem, (_Float16*)(smem + 9216));
    } else {
        concepts64(blk - 768, Abf, BbfT, rowtok, nbias, C, smem);
    }
}

// ---------------- em2k: S2 = hh @ WT2 + b2 (f32) ----------------
__global__ __launch_bounds__(256) void em2k(const _Float16* __restrict__ hh,
                                            const _Float16* __restrict__ WT2,
                                            const float* __restrict__ b2,
                                            float* __restrict__ S2) {
    __shared__ __align__(16) _Float16 As[2 * 2304];
    __shared__ __align__(16) _Float16 Bs[2 * 2304];
    int u = blockIdx.x;
    int bm = (u % 12) * 32, bn = (u / 12) * 32;
    emgemm_body256<0>(hh, WT2, b2, S2, nullptr, bm, bn, As, Bs);
}

// ---------------- block reductions (256 threads = 4 waves) ----------------
__device__ __forceinline__ float bred_sum(float x, float* sbuf) {
#pragma unroll
    for (int off = 32; off; off >>= 1) x += __shfl_down(x, off);
    __syncthreads();
    if ((threadIdx.x & 63) == 0) sbuf[threadIdx.x >> 6] = x;
    __syncthreads();
    return sbuf[0] + sbuf[1] + sbuf[2] + sbuf[3];
}
__device__ __forceinline__ float bred_max(float x, float* sbuf) {
#pragma unroll
    for (int off = 32; off; off >>= 1) x = fmaxf(x, __shfl_down(x, off));
    __syncthreads();
    if ((threadIdx.x & 63) == 0) sbuf[threadIdx.x >> 6] = x;
    __syncthreads();
    return fmaxf(fmaxf(sbuf[0], sbuf[1]), fmaxf(sbuf[2], sbuf[3]));
}

// ---------------- rowops: softmax(S2), l2norm(Tr) -> fp16 uh,vh,rh,th,t2h; inv norms ----
__global__ __launch_bounds__(256) void rowops(const float* __restrict__ S2,
                                              const float* __restrict__ Tr,
                                              const float* __restrict__ rr,
                                              const float* __restrict__ tt,
                                              _Float16* __restrict__ uh, _Float16* __restrict__ vh,
                                              _Float16* __restrict__ rh, _Float16* __restrict__ th,
                                              _Float16* __restrict__ t2h,
                                              float* __restrict__ inv_r,
                                              float* __restrict__ inv_t) {
    __shared__ float sbuf[4];
    const int b = blockIdx.x, tid = threadIdx.x;
    const size_t base = (size_t)b * DDIM + tid * 4;

    const float4 s4 = *(const float4*)&S2[base];
    float mx = fmaxf(fmaxf(s4.x, s4.y), fmaxf(s4.z, s4.w));
    mx = bred_max(mx, sbuf);
    float e0 = expf(s4.x - mx), e1 = expf(s4.y - mx), e2 = expf(s4.z - mx), e3 = expf(s4.w - mx);
    float sum = bred_sum(e0 + e1 + e2 + e3, sbuf);
    float invsum = 1.f / sum;

    const float4 tr4 = *(const float4*)&Tr[base];
    float ss = tr4.x * tr4.x + tr4.y * tr4.y + tr4.z * tr4.z + tr4.w * tr4.w;
    ss = bred_sum(ss, sbuf);
    float invn = 1.f / sqrtf(ss);

    float a0 = e0 * invsum, a1 = e1 * invsum, a2 = e2 * invsum, a3 = e3 * invsum;
    union { _Float16 h[4]; ushort4 u; } o;

    o.h[0] = (_Float16)(tr4.x * invn * a0 * 1024.f);
    o.h[1] = (_Float16)(tr4.y * invn * a1 * 1024.f);
    o.h[2] = (_Float16)(tr4.z * invn * a2 * 1024.f);
    o.h[3] = (_Float16)(tr4.w * invn * a3 * 1024.f);
    *(ushort4*)&uh[base] = o.u;

    float q0 = a0 * 32.f, q1 = a1 * 32.f, q2 = a2 * 32.f, q3 = a3 * 32.f;
    o.h[0] = (_Float16)(q0 * q0); o.h[1] = (_Float16)(q1 * q1);
    o.h[2] = (_Float16)(q2 * q2); o.h[3] = (_Float16)(q3 * q3);
    *(ushort4*)&vh[base] = o.u;

    const float4 r4 = *(const float4*)&rr[base];
    o.h[0] = (_Float16)r4.x; o.h[1] = (_Float16)r4.y;
    o.h[2] = (_Float16)r4.z; o.h[3] = (_Float16)r4.w;
    *(ushort4*)&rh[base] = o.u;

    const float4 t4 = *(const float4*)&tt[base];
    o.h[0] = (_Float16)t4.x; o.h[1] = (_Float16)t4.y;
    o.h[2] = (_Float16)t4.z; o.h[3] = (_Float16)t4.w;
    *(ushort4*)&th[base] = o.u;

    o.h[0] = (_Float16)(t4.x * t4.x); o.h[1] = (_Float16)(t4.y * t4.y);
    o.h[2] = (_Float16)(t4.z * t4.z); o.h[3] = (_Float16)(t4.w * t4.w);
    *(ushort4*)&t2h[base] = o.u;

    float sr = bred_sum(r4.x * r4.x + r4.y * r4.y + r4.z * r4.z + r4.w * r4.w, sbuf);
    float st = bred_sum(t4.x * t4.x + t4.y * t4.y + t4.z * t4.z + t4.w * t4.w, sbuf);
    if (tid == 0) {
        inv_r[b] = 1.f / sqrtf(sr);
        inv_t[b] = 1.f / sqrtf(st);
    }
}

// ---------------- score: fp16 MFMA, 3 dots, 32x32 tile, K-step 64, dbuf — r6 proven -------
__global__ __launch_bounds__(128) void score_mfma(const _Float16* __restrict__ uh,
                                                  const _Float16* __restrict__ vh,
                                                  const _Float16* __restrict__ rh,
                                                  const _Float16* __restrict__ th,
                                                  const _Float16* __restrict__ t2h,
                                                  const float* __restrict__ inv_r,
                                                  const float* __restrict__ inv_t,
                                                  float* __restrict__ out) {
    __shared__ __align__(16) _Float16 Us[2][32 * 72];
    __shared__ __align__(16) _Float16 Vs[2][32 * 72];
    __shared__ __align__(16) _Float16 Rs[2][32 * 72];
    __shared__ __align__(16) _Float16 Ts[2][32 * 72];
    __shared__ __align__(16) _Float16 Qs[2][32 * 72];

    const int tid = threadIdx.x;
    const int bm = blockIdx.x * 32, bn = blockIdx.y * 32;
    const int lane = tid & 63;
    const int wrow = (tid >> 6) * 16;
    const int frow = lane & 15, fk = lane >> 4;
    const int srow = tid >> 2, spart = tid & 3;

    f32x4 an0 = {0.f, 0.f, 0.f, 0.f}, an1 = an0;
    f32x4 ad0 = an0, ad1 = an0, ai0 = an0, ai1 = an0;
    int4 pu0, pu1, pv0, pv1, pr0, pr1, pt0, pt1, pq0, pq1;
    constexpr int NK = DDIM / 64;  // 16

#define S_LOAD(ks)                                                                   \
    {                                                                                \
        const size_t mo = (size_t)(bm + srow) * DDIM + (ks) * 64 + spart * 16;       \
        const size_t no = (size_t)(bn + srow) * DDIM + (ks) * 64 + spart * 16;       \
        pu0 = *(const int4*)&uh[mo];  pu1 = *(const int4*)&uh[mo + 8];               \
        pv0 = *(const int4*)&vh[mo];  pv1 = *(const int4*)&vh[mo + 8];               \
        pr0 = *(const int4*)&rh[mo];  pr1 = *(const int4*)&rh[mo + 8];               \
        pt0 = *(const int4*)&th[no];  pt1 = *(const int4*)&th[no + 8];               \
        pq0 = *(const int4*)&t2h[no]; pq1 = *(const int4*)&t2h[no + 8];              \
    }
#define S_STORE(buf)                                                                 \
    {                                                                                \
        const int lo = srow * 72 + spart * 16;                                       \
        *(int4*)&Us[buf][lo] = pu0; *(int4*)&Us[buf][lo + 8] = pu1;                  \
        *(int4*)&Vs[buf][lo] = pv0; *(int4*)&Vs[buf][lo + 8] = pv1;                  \
        *(int4*)&Rs[buf][lo] = pr0; *(int4*)&Rs[buf][lo + 8] = pr1;                  \
        *(int4*)&Ts[buf][lo] = pt0; *(int4*)&Ts[buf][lo + 8] = pt1;                  \
        *(int4*)&Qs[buf][lo] = pq0; *(int4*)&Qs[buf][lo + 8] = pq1;                  \
    }

    S_LOAD(0);
    S_STORE(0);
    __syncthreads();
    int cur = 0;

    for (int ks = 0; ks < NK; ++ks) {
        if (ks + 1 < NK) S_LOAD(ks + 1);
#pragma unroll
        for (int kk = 0; kk < 2; ++kk) {
            const int ao = (wrow + frow) * 72 + kk * 32 + fk * 8;
            const int bo0 = frow * 72 + kk * 32 + fk * 8;
            const int bo1 = (16 + frow) * 72 + kk * 32 + fk * 8;
            half8 au = *(const half8*)&Us[cur][ao];
            half8 av = *(const half8*)&Vs[cur][ao];
            half8 ar = *(const half8*)&Rs[cur][ao];
            half8 bt0 = *(const half8*)&Ts[cur][bo0];
            half8 bt1 = *(const half8*)&Ts[cur][bo1];
            half8 bq0 = *(const half8*)&Qs[cur][bo0];
            half8 bq1 = *(const half8*)&Qs[cur][bo1];
            an0 = __builtin_amdgcn_mfma_f32_16x16x32_f16(au, bt0, an0, 0, 0, 0);
            an1 = __builtin_amdgcn_mfma_f32_16x16x32_f16(au, bt1, an1, 0, 0, 0);
            ad0 = __builtin_amdgcn_mfma_f32_16x16x32_f16(av, bq0, ad0, 0, 0, 0);
            ad1 = __builtin_amdgcn_mfma_f32_16x16x32_f16(av, bq1, ad1, 0, 0, 0);
            ai0 = __builtin_amdgcn_mfma_f32_16x16x32_f16(ar, bt0, ai0, 0, 0, 0);
            ai1 = __builtin_amdgcn_mfma_f32_16x16x32_f16(ar, bt1, ai1, 0, 0, 0);
        }
        if (ks + 1 < NK) S_STORE(cur ^ 1);
        __syncthreads();
        cur ^= 1;
    }
#undef S_LOAD
#undef S_STORE

    const int orow0 = bm + wrow + fk * 4;
    const int c0 = bn + frow, c1 = bn + 16 + frow;
    const float it0 = inv_t[c0], it1 = inv_t[c1];
#pragma unroll
    for (int r = 0; r < 4; ++r) {
        int row = orow0 + r;
        float ir = inv_r[row];
        float em0 = an0[r] / (32.f * sqrtf(ad0[r]));
        float em1 = an1[r] / (32.f * sqrtf(ad1[r]));
        out[(size_t)row * BDIM + c0] = em0 + ai0[r] * ir * it0;
        out[(size_t)row * BDIM + c1] = em1 + ai1[r] * ir * it1;
    }
}

extern "C" void kernel_launch(void* const* d_in, const int* in_sizes, int n_in, void* d_out,
                              int out_size, void* d_ws, size_t ws_size, hipStream_t stream) {
    const float* r = (const float*)d_in[0];
    const float* m = (const float*)d_in[1];
    const float* t = (const float*)d_in[2];
    const int* ntid = (const int*)d_in[3];
    const int* nlen = (const int*)d_in[4];
    const int* ant = (const int*)d_in[5];
    const float* embed = (const float*)d_in[6];
    const float* noun_W = (const float*)d_in[7];
    const float* noun_b = (const float*)d_in[8];
    const float* em_W1 = (const float*)d_in[9];
    const float* em_b1 = (const float*)d_in[10];
    const float* em_W2 = (const float*)d_in[11];
    const float* em_b2 = (const float*)d_in[12];
    const float* tr_W = (const float*)d_in[13];
    const float* tr_b = (const float*)d_in[14];
    const int* t2i = (const int*)d_in[15];

    float* score = (float*)d_out;
    float* concepts = score + (size_t)SELEM;

    // ---- flat workspace layout (~19.4 MB; observed ws_size ~268 MB) ----
    char* base = (char*)d_ws;
    size_t off = 0;
    auto alloc = [&](size_t bytes) { char* p = base + off; off += (bytes + 255) & ~(size_t)255; return p; };
    int* rowtok = (int*)alloc(NROWS * 4);
    float* inv_r = (float*)alloc(BDIM * 4);
    float* inv_t = (float*)alloc(BDIM * 4);
    ushort* Abf = (ushort*)alloc((size_t)NROWS * CK * 2);
    ushort* BbfT = (ushort*)alloc((size_t)DDIM * CK * 2);
    _Float16* WT1 = (_Float16*)alloc((size_t)DDIM * DDIM * 2);
    _Float16* WT2 = (_Float16*)alloc((size_t)DDIM * DDIM * 2);
    _Float16* WT3 = (_Float16*)alloc((size_t)DDIM * DDIM * 2);
    _Float16* mh = (_Float16*)alloc((size_t)FELEM * 2);
    _Float16* hh = (_Float16*)alloc((size_t)FELEM * 2);
    float* S2 = (float*)alloc((size_t)FELEM * 4);
    float* Tr = (float*)alloc((size_t)FELEM * 4);
    _Float16* uh = (_Float16*)alloc((size_t)FELEM * 2);
    _Float16* vh = (_Float16*)alloc((size_t)FELEM * 2);
    _Float16* rh = (_Float16*)alloc((size_t)FELEM * 2);
    _Float16* th = (_Float16*)alloc((size_t)FELEM * 2);
    _Float16* t2h = (_Float16*)alloc((size_t)FELEM * 2);

    prep_all<<<PRE_M, 256, 0, stream>>>(embed, ntid, nlen, ant, t2i, Abf, rowtok,
                                        noun_W, BbfT, em_W1, em_W2, tr_W, WT1, WT2, WT3,
                                        m, mh);

    mega1<<<2304, 256, 0, stream>>>(mh, WT1, WT3, em_b1, tr_b, hh, Tr,
                                    Abf, BbfT, rowtok, noun_b, concepts);

    em2k<<<384, 256, 0, stream>>>(hh, WT2, em_b2, S2);

    rowops<<<BDIM, 256, 0, stream>>>(S2, Tr, r, t, uh, vh, rh, th, t2h, inv_r, inv_t);

    dim3 gS(BDIM / 32, BDIM / 32);      // 12 x 12
    score_mfma<<<gS, 128, 0, stream>>>(uh, vh, rh, th, t2h, inv_r, inv_t, score);
}